// Round 10
// baseline (396.161 us; speedup 1.0000x reference)
//
#include <hip/hip_runtime.h>
#include <hip/hip_cooperative_groups.h>

namespace cg = cooperative_groups;

#define Bz 4
#define Nn 1024
#define Dd 1024
#define Hh 16
#define HD 64
#define SCALE 0.125f
#define LN_EPS 1e-5f

typedef __attribute__((ext_vector_type(8))) __bf16 bf16x8;
typedef __attribute__((ext_vector_type(4))) float f32x4;

static __device__ inline unsigned short f2bf(float f) {
    unsigned int u = __float_as_uint(f);
    u += 0x7fffu + ((u >> 16) & 1u);   // round-to-nearest-even
    return (unsigned short)(u >> 16);
}

static __device__ inline bf16x8 ldfrag(const unsigned short* p) {
    return *(const bf16x8*)p;
}

static __device__ __forceinline__ void glds16(const unsigned short* g, unsigned short* l) {
    __builtin_amdgcn_global_load_lds((const __attribute__((address_space(1))) void*)g,
                                     (__attribute__((address_space(3))) void*)l, 16, 0, 0);
}

// ---------------- phase 0: LN + weight transposes (8192 virt / 512) -------
static __device__ __forceinline__ void phase_prep(unsigned short* smem, int bid, int tid,
        const float* __restrict__ x, const float* __restrict__ gamma,
        const float* __restrict__ beta, unsigned short* __restrict__ xn,
        const float* __restrict__ w_qkv, unsigned short* __restrict__ wqkvT,
        const float* __restrict__ w_proj, unsigned short* __restrict__ wprojT) {
    float* tile = (float*)smem;                 // [32][33]
    for (int blk = bid; blk < 8192; blk += 512) {
        if (blk < 4096) {
            const float* xr = x + (size_t)blk * Dd;
            float4 v = ((const float4*)xr)[tid];
            float s = v.x + v.y + v.z + v.w;
            float ss = v.x * v.x + v.y * v.y + v.z * v.z + v.w * v.w;
            for (int o = 32; o > 0; o >>= 1) {
                s += __shfl_down(s, o);
                ss += __shfl_down(ss, o);
            }
            int wid = tid >> 6;
            if ((tid & 63) == 0) { tile[wid * 2] = s; tile[wid * 2 + 1] = ss; }
            __syncthreads();
            float tot = tile[0] + tile[2] + tile[4] + tile[6];
            float tot2 = tile[1] + tile[3] + tile[5] + tile[7];
            float mu = tot * (1.0f / Dd);
            float var = tot2 * (1.0f / Dd) - mu * mu;
            float inv = rsqrtf(var + LN_EPS);
            float4 g = ((const float4*)gamma)[tid];
            float4 b = ((const float4*)beta)[tid];
            ushort4 o4;
            o4.x = f2bf((v.x - mu) * inv * g.x + b.x);
            o4.y = f2bf((v.y - mu) * inv * g.y + b.y);
            o4.z = f2bf((v.z - mu) * inv * g.z + b.z);
            o4.w = f2bf((v.w - mu) * inv * g.w + b.w);
            ((ushort4*)(xn + (size_t)blk * Dd))[tid] = o4;
        } else {
            const float* in;
            unsigned short* outp;
            int cols, c0, r0;
            if (blk < 7168) {
                int idx = blk - 4096;
                in = w_qkv; outp = wqkvT; cols = 3072;
                c0 = (idx % 96) * 32; r0 = (idx / 96) * 32;
            } else {
                int idx = blk - 7168;
                in = w_proj; outp = wprojT; cols = 1024;
                c0 = (idx % 32) * 32; r0 = (idx / 32) * 32;
            }
            int tx = tid & 31, ty = tid >> 5;
            #pragma unroll
            for (int i = 0; i < 32; i += 8)
                tile[(ty + i) * 33 + tx] = in[(size_t)(r0 + ty + i) * cols + c0 + tx];
            __syncthreads();
            #pragma unroll
            for (int i = 0; i < 32; i += 8)
                outp[(size_t)(c0 + ty + i) * 1024 + r0 + tx] = f2bf(tile[tx * 33 + ty + i]);
        }
        __syncthreads();
    }
}

// --------- phase 1: qkv GEMM, 128x96 tile (1024 tiles, 2 per block) -------
static __device__ __forceinline__ void phase_qkv(unsigned short* smem, int t, int tid,
        const unsigned short* __restrict__ A, const unsigned short* __restrict__ Bt,
        unsigned short* __restrict__ qb, unsigned short* __restrict__ kb,
        unsigned short* __restrict__ vtb) {
    unsigned short* sA = smem;            // [128][64] = 8192 shorts
    unsigned short* sB = smem + 8192;     // [96][64]  = 6144 shorts
    int w = tid >> 6, lane = tid & 63, lrow = lane & 15, quad = lane >> 4;
    int wm = w >> 1, wn = w & 1;
    int rowbase = (t >> 5) * 128;
    int colbase = (t & 31) * 96;

    int srow = tid >> 3;
    int gch = ((tid & 7) - (srow >> 1)) & 7;
    const unsigned short* gA = A + (size_t)(rowbase + srow) * 1024 + gch * 8;
    const unsigned short* gB = Bt + (size_t)(colbase + srow) * 1024 + gch * 8;
    unsigned short* lA = sA + w * 512;
    unsigned short* lB = sB + w * 512;

    int bs0 = ((quad + (lrow >> 1)) & 7) * 8;
    int bs1 = ((4 + quad + (lrow >> 1)) & 7) * 8;
    const unsigned short* fa = sA + (wm * 64 + lrow) * 64;
    const unsigned short* fb = sB + (wn * 48 + lrow) * 64;

    f32x4 acc[4][3];
    #pragma unroll
    for (int i = 0; i < 4; i++)
        #pragma unroll
        for (int j = 0; j < 3; j++)
            acc[i][j] = (f32x4){0.f, 0.f, 0.f, 0.f};

    for (int k0 = 0; k0 < 1024; k0 += 64) {
        __syncthreads();
        #pragma unroll
        for (int c = 0; c < 4; c++)
            glds16(gA + (size_t)c * 32768 + k0, lA + c * 2048);
        #pragma unroll
        for (int c = 0; c < 3; c++)
            glds16(gB + (size_t)c * 32768 + k0, lB + c * 2048);
        __syncthreads();
        #pragma unroll
        for (int s = 0; s < 2; s++) {
            int bo = s ? bs1 : bs0;
            bf16x8 a[4], b[3];
            #pragma unroll
            for (int i = 0; i < 4; i++) a[i] = *(const bf16x8*)(fa + i * 1024 + bo);
            #pragma unroll
            for (int j = 0; j < 3; j++) b[j] = *(const bf16x8*)(fb + j * 1024 + bo);
            #pragma unroll
            for (int i = 0; i < 4; i++)
                #pragma unroll
                for (int j = 0; j < 3; j++)
                    acc[i][j] = __builtin_amdgcn_mfma_f32_16x16x32_bf16(a[i], b[j], acc[i][j], 0, 0, 0);
        }
    }

    #pragma unroll
    for (int j = 0; j < 3; j++) {
        int colg = colbase + wn * 48 + j * 16;
        int s = colg >> 10, rem = colg & 1023;
        int h = rem >> 6;
        int e = (rem & 63) + lrow;
        if (s < 2) {
            unsigned short* dst = (s == 0) ? qb : kb;
            #pragma unroll
            for (int i = 0; i < 4; i++) {
                #pragma unroll
                for (int r = 0; r < 4; r++) {
                    int R = rowbase + wm * 64 + i * 16 + quad * 4 + r;
                    int bb = R >> 10, n = R & 1023;
                    dst[(((size_t)(bb * Hh + h)) * Nn + n) * HD + e] = f2bf(acc[i][j][r]);
                }
            }
        } else {
            // v: lane's r=0..3 are consecutive tokens n -> packed 8B store
            #pragma unroll
            for (int i = 0; i < 4; i++) {
                int R0 = rowbase + wm * 64 + i * 16 + quad * 4;
                int bb = R0 >> 10, n0v = R0 & 1023;
                uint2 pk;
                pk.x = (unsigned)f2bf(acc[i][j][0]) | ((unsigned)f2bf(acc[i][j][1]) << 16);
                pk.y = (unsigned)f2bf(acc[i][j][2]) | ((unsigned)f2bf(acc[i][j][3]) << 16);
                *(uint2*)(vtb + ((size_t)((bb * Hh + h) * HD) + e) * Nn + n0v) = pk;
            }
        }
    }
}

// --------- phase 2: attn (v4 body, 32 KB: sP XOR-swizzled, exp2f) ---------
static __device__ __forceinline__ void phase_attn(unsigned short* smem, int bid, int tid,
        const unsigned short* __restrict__ qb, const unsigned short* __restrict__ kb,
        const unsigned short* __restrict__ vtb, const float* __restrict__ sim,
        const float* __restrict__ swl, unsigned short* __restrict__ aout) {
    int nt = bid & 7, h = (bid >> 3) & 15, bb = bid >> 7;
    int n0 = nt * 128;
    int w = tid >> 6, lane = tid & 63, lrow = lane & 15, quad = lane >> 4;
    const unsigned short* q = qb + ((size_t)(bb * Hh + h)) * Nn * HD;
    const unsigned short* k = kb + ((size_t)(bb * Hh + h)) * Nn * HD;
    const unsigned short* vt = vtb + ((size_t)(bb * Hh + h)) * HD * Nn;
    float alpha = 1.f / (1.f + __expf(-swl[0]));
    const float L2E = 1.44269504f;
    float c1 = (1.f - alpha) * SCALE * L2E;
    float aL = alpha * L2E;

    unsigned short* sK = smem;            // [64 keys][64 d]
    unsigned short* sV = smem + 4096;     // [64 e][64 keys]
    unsigned short* sP = smem + 8192;     // [128 qrows][64 keys], XOR-swizzled

    int qr0 = n0 + w * 32;
    bf16x8 qf[2][2];
    #pragma unroll
    for (int g = 0; g < 2; g++) {
        qf[g][0] = ldfrag(q + (size_t)(qr0 + g * 16 + lrow) * HD + quad * 8);
        qf[g][1] = ldfrag(q + (size_t)(qr0 + g * 16 + lrow) * HD + 32 + quad * 8);
    }

    f32x4 o[2][4];
    #pragma unroll
    for (int g = 0; g < 2; g++)
        #pragma unroll
        for (int et = 0; et < 4; et++) o[g][et] = (f32x4){0.f, 0.f, 0.f, 0.f};
    float rsum[2] = {0.f, 0.f};

    int bs0 = (quad + (lrow >> 1)) & 7;
    int bs1 = (4 + quad + (lrow >> 1)) & 7;
    unsigned short* sPw = sP + (w * 32) * 64;
    int psw = lrow & 7;                   // sP chunk-XOR key (row-derived)
    int wrc = quad >> 1, wrh = quad & 1;  // write chunk parity / half

    for (int m0 = 0; m0 < 1024; m0 += 64) {
        __syncthreads();
        #pragma unroll
        for (int i = 0; i < 2; i++) {
            int slot = i * 256 + tid;
            int row = slot >> 3;
            int cg2 = ((slot & 7) - (row >> 1)) & 7;
            glds16(k + (size_t)(m0 + row) * HD + cg2 * 8, sK + i * 2048 + w * 512);
        }
        #pragma unroll
        for (int i = 0; i < 2; i++) {
            int slot = i * 256 + tid;
            int row = slot >> 3;
            int cg2 = ((slot & 7) - (row >> 1)) & 7;
            glds16(vt + (size_t)row * Nn + m0 + cg2 * 8, sV + i * 2048 + w * 512);
        }
        float4 sm[4][2];
        #pragma unroll
        for (int ks = 0; ks < 4; ks++)
            #pragma unroll
            for (int g = 0; g < 2; g++)
                sm[ks][g] = *(const float4*)(sim + (size_t)(qr0 + g * 16 + lrow) * Nn
                                             + m0 + ks * 16 + quad * 4);
        __syncthreads();

        #pragma unroll
        for (int ks = 0; ks < 4; ks++) {
            const unsigned short* kr = sK + (ks * 16 + lrow) * 64;
            bf16x8 ak0 = *(const bf16x8*)(kr + bs0 * 8);
            bf16x8 ak1 = *(const bf16x8*)(kr + bs1 * 8);
            int cc = ((ks * 2 + wrc) ^ psw);
            #pragma unroll
            for (int g = 0; g < 2; g++) {
                f32x4 c = (f32x4){0.f, 0.f, 0.f, 0.f};
                c = __builtin_amdgcn_mfma_f32_16x16x32_bf16(ak0, qf[g][0], c, 0, 0, 0);
                c = __builtin_amdgcn_mfma_f32_16x16x32_bf16(ak1, qf[g][1], c, 0, 0, 0);
                float e0 = exp2f(c1 * c[0] + aL * sm[ks][g].x);
                float e1 = exp2f(c1 * c[1] + aL * sm[ks][g].y);
                float e2 = exp2f(c1 * c[2] + aL * sm[ks][g].z);
                float e3 = exp2f(c1 * c[3] + aL * sm[ks][g].w);
                rsum[g] += (e0 + e1) + (e2 + e3);
                uint2 pk;
                pk.x = (__float_as_uint(e0) >> 16) | (__float_as_uint(e1) & 0xffff0000u);
                pk.y = (__float_as_uint(e2) >> 16) | (__float_as_uint(e3) & 0xffff0000u);
                *(uint2*)(sPw + (g * 16 + lrow) * 64 + cc * 8 + wrh * 4) = pk;
            }
        }

        #pragma unroll
        for (int ms = 0; ms < 2; ms++) {
            bf16x8 pa[2];
            #pragma unroll
            for (int g = 0; g < 2; g++)
                pa[g] = *(const bf16x8*)(sPw + (g * 16 + lrow) * 64
                                         + ((ms * 4 + quad) ^ psw) * 8);
            #pragma unroll
            for (int et = 0; et < 4; et++) {
                int e = et * 16 + lrow;
                int slot = (ms * 4 + quad + (e >> 1)) & 7;
                bf16x8 vb = *(const bf16x8*)(sV + e * 64 + slot * 8);
                #pragma unroll
                for (int g = 0; g < 2; g++)
                    o[g][et] = __builtin_amdgcn_mfma_f32_16x16x32_bf16(pa[g], vb, o[g][et], 0, 0, 0);
            }
        }
    }

    #pragma unroll
    for (int g = 0; g < 2; g++) {
        rsum[g] += __shfl_xor(rsum[g], 16);
        rsum[g] += __shfl_xor(rsum[g], 32);
    }

    #pragma unroll
    for (int g = 0; g < 2; g++)
        #pragma unroll
        for (int r = 0; r < 4; r++) {
            float inv = 1.f / __shfl(rsum[g], quad * 4 + r);
            int qn = qr0 + g * 16 + quad * 4 + r;
            #pragma unroll
            for (int et = 0; et < 4; et++)
                aout[((size_t)bb * Nn + qn) * Dd + h * HD + et * 16 + lrow]
                    = f2bf(o[g][et][r] * inv);
        }
}

// --------- phase 3: proj GEMM 64x128 (512 tiles) + bias + residual --------
static __device__ __forceinline__ void phase_proj(unsigned short* smem, int bid, int tid,
        const unsigned short* __restrict__ A, const unsigned short* __restrict__ Bt,
        const float* __restrict__ bias, const float* __restrict__ x,
        float* __restrict__ out) {
    unsigned short* sA = smem;            // [64][64]  = 4096 shorts
    unsigned short* sB = smem + 4096;     // [128][64] = 8192 shorts
    int w = tid >> 6, lane = tid & 63, lrow = lane & 15, quad = lane >> 4;
    int wm = w >> 1, wn = w & 1;
    int rowbase = (bid >> 3) * 64;
    int colbase = (bid & 7) * 128;

    int srow = tid >> 3;
    int gch = ((tid & 7) - (srow >> 1)) & 7;
    const unsigned short* gA = A + (size_t)(rowbase + srow) * 1024 + gch * 8;
    const unsigned short* gB = Bt + (size_t)(colbase + srow) * 1024 + gch * 8;
    unsigned short* lA = sA + w * 512;
    unsigned short* lB = sB + w * 512;

    int bs0 = ((quad + (lrow >> 1)) & 7) * 8;
    int bs1 = ((4 + quad + (lrow >> 1)) & 7) * 8;
    const unsigned short* fa = sA + (wm * 32 + lrow) * 64;
    const unsigned short* fb = sB + (wn * 64 + lrow) * 64;

    f32x4 acc[2][4];
    #pragma unroll
    for (int i = 0; i < 2; i++)
        #pragma unroll
        for (int j = 0; j < 4; j++)
            acc[i][j] = (f32x4){0.f, 0.f, 0.f, 0.f};

    for (int k0 = 0; k0 < 1024; k0 += 64) {
        __syncthreads();
        #pragma unroll
        for (int c = 0; c < 2; c++)
            glds16(gA + (size_t)c * 32768 + k0, lA + c * 2048);
        #pragma unroll
        for (int c = 0; c < 4; c++)
            glds16(gB + (size_t)c * 32768 + k0, lB + c * 2048);
        __syncthreads();
        #pragma unroll
        for (int s = 0; s < 2; s++) {
            int bo = s ? bs1 : bs0;
            bf16x8 a[2], b[4];
            #pragma unroll
            for (int i = 0; i < 2; i++) a[i] = *(const bf16x8*)(fa + i * 1024 + bo);
            #pragma unroll
            for (int j = 0; j < 4; j++) b[j] = *(const bf16x8*)(fb + j * 1024 + bo);
            #pragma unroll
            for (int i = 0; i < 2; i++)
                #pragma unroll
                for (int j = 0; j < 4; j++)
                    acc[i][j] = __builtin_amdgcn_mfma_f32_16x16x32_bf16(a[i], b[j], acc[i][j], 0, 0, 0);
        }
    }

    #pragma unroll
    for (int j = 0; j < 4; j++) {
        int col = colbase + wn * 64 + j * 16 + lrow;
        float bc = bias[col];
        #pragma unroll
        for (int i = 0; i < 2; i++) {
            #pragma unroll
            for (int r = 0; r < 4; r++) {
                int R = rowbase + wm * 32 + i * 16 + quad * 4 + r;
                out[(size_t)R * 1024 + col] = acc[i][j][r] + bc + x[(size_t)R * 1024 + col];
            }
        }
    }
}

// ====================== cooperative mega: 512 x 256 ========================
__global__ __launch_bounds__(256, 2) void mega(const float* x, const float* gamma,
        const float* beta, const float* w_qkv, const float* w_proj,
        const float* b_proj, const float* swl, const float* sim, float* out,
        unsigned short* xn, unsigned short* wqkvT, unsigned short* wprojT,
        unsigned short* qb, unsigned short* kb, unsigned short* vtb,
        unsigned short* aout) {
    cg::grid_group grid = cg::this_grid();
    __shared__ __align__(16) unsigned short smem[16384];   // 32 KB
    int tid = threadIdx.x, bid = blockIdx.x;

    phase_prep(smem, bid, tid, x, gamma, beta, xn, w_qkv, wqkvT, w_proj, wprojT);
    grid.sync();
    phase_qkv(smem, bid, tid, xn, wqkvT, qb, kb, vtb);
    phase_qkv(smem, bid + 512, tid, xn, wqkvT, qb, kb, vtb);
    grid.sync();
    phase_attn(smem, bid, tid, qb, kb, vtb, sim, swl, aout);
    grid.sync();
    phase_proj(smem, bid, tid, aout, wprojT, b_proj, x, out);
}

// ------------------- standalone fallback kernels ---------------------------
__global__ __launch_bounds__(256) void k_prep(const float* x, const float* gamma,
        const float* beta, unsigned short* xn, const float* w_qkv,
        unsigned short* wqkvT, const float* w_proj, unsigned short* wprojT) {
    __shared__ __align__(16) unsigned short smem[16384];
    phase_prep(smem, blockIdx.x, threadIdx.x, x, gamma, beta, xn, w_qkv, wqkvT, w_proj, wprojT);
}
__global__ __launch_bounds__(256) void k_qkv(const unsigned short* A,
        const unsigned short* Bt, unsigned short* qb, unsigned short* kb,
        unsigned short* vtb) {
    __shared__ __align__(16) unsigned short smem[16384];
    phase_qkv(smem, blockIdx.x, threadIdx.x, A, Bt, qb, kb, vtb);
    phase_qkv(smem, blockIdx.x + 512, threadIdx.x, A, Bt, qb, kb, vtb);
}
__global__ __launch_bounds__(256) void k_attn(const unsigned short* qb,
        const unsigned short* kb, const unsigned short* vtb, const float* sim,
        const float* swl, unsigned short* aout) {
    __shared__ __align__(16) unsigned short smem[16384];
    phase_attn(smem, blockIdx.x, threadIdx.x, qb, kb, vtb, sim, swl, aout);
}
__global__ __launch_bounds__(256) void k_proj(const unsigned short* A,
        const unsigned short* Bt, const float* bias, const float* x, float* out) {
    __shared__ __align__(16) unsigned short smem[16384];
    phase_proj(smem, blockIdx.x, threadIdx.x, A, Bt, bias, x, out);
}

extern "C" void kernel_launch(void* const* d_in, const int* in_sizes, int n_in,
                              void* d_out, int out_size, void* d_ws, size_t ws_size,
                              hipStream_t stream) {
    const float* x      = (const float*)d_in[0];
    const float* gamma  = (const float*)d_in[1];
    const float* beta   = (const float*)d_in[2];
    const float* w_qkv  = (const float*)d_in[3];
    const float* w_proj = (const float*)d_in[4];
    const float* b_proj = (const float*)d_in[5];
    const float* swl    = (const float*)d_in[6];
    const float* sim    = (const float*)d_in[7];
    float* out = (float*)d_out;

    unsigned short* ws = (unsigned short*)d_ws;
    unsigned short* xn     = ws;                  // 4096*1024
    unsigned short* wqkvT  = xn + 4194304;        // 3072*1024
    unsigned short* wprojT = wqkvT + 3145728;     // 1024*1024
    unsigned short* qb     = wprojT + 1048576;    // 4*16*1024*64
    unsigned short* kb     = qb + 4194304;
    unsigned short* vtb    = kb + 4194304;
    unsigned short* aout   = vtb + 4194304;       // 4096*1024

    void* args[] = {
        (void*)&x, (void*)&gamma, (void*)&beta, (void*)&w_qkv, (void*)&w_proj,
        (void*)&b_proj, (void*)&swl, (void*)&sim, (void*)&out,
        (void*)&xn, (void*)&wqkvT, (void*)&wprojT,
        (void*)&qb, (void*)&kb, (void*)&vtb, (void*)&aout
    };
    hipError_t err = hipLaunchCooperativeKernel((const void*)mega, dim3(512), dim3(256),
                                                args, 0, stream);
    if (err != hipSuccess) {
        (void)hipGetLastError();   // clear sticky error; fall back to 4 launches
        k_prep<<<512, 256, 0, stream>>>(x, gamma, beta, xn, w_qkv, wqkvT, w_proj, wprojT);
        k_qkv<<<512, 256, 0, stream>>>(xn, wqkvT, qb, kb, vtb);
        k_attn<<<512, 256, 0, stream>>>(qb, kb, vtb, sim, swl, aout);
        k_proj<<<512, 256, 0, stream>>>(aout, wprojT, b_proj, x, out);
    }
}

// Round 11
// 205.533 us; speedup vs baseline: 1.9275x; 1.9275x over previous
//
#include <hip/hip_runtime.h>
#include <hip/hip_bf16.h>

#define Bz 4
#define Nn 1024
#define Dd 1024
#define Hh 16
#define HD 64
#define SCALE 0.125f
#define LN_EPS 1e-5f

typedef __attribute__((ext_vector_type(8))) __bf16 bf16x8;
typedef __attribute__((ext_vector_type(4))) float f32x4;

static __device__ inline unsigned short f2bf(float f) {
    unsigned int u = __float_as_uint(f);
    u += 0x7fffu + ((u >> 16) & 1u);   // round-to-nearest-even
    return (unsigned short)(u >> 16);
}

static __device__ inline unsigned pack2bf(float a, float b) {
    __hip_bfloat162 h = __float22bfloat162_rn(make_float2(a, b));  // v_cvt_pk_bf16_f32
    unsigned u;
    __builtin_memcpy(&u, &h, 4);
    return u;
}

static __device__ inline bf16x8 ldfrag(const unsigned short* p) {
    return *(const bf16x8*)p;
}

static __device__ __forceinline__ void glds16(const unsigned short* g, unsigned short* l) {
    __builtin_amdgcn_global_load_lds((const __attribute__((address_space(1))) void*)g,
                                     (__attribute__((address_space(3))) void*)l, 16, 0, 0);
}

// ===== prep: LN (blocks 0..4095) + transpose w_qkv (4096..7167) +
//             transpose w_proj (7168..8191), all 256-thread blocks ==========
__global__ __launch_bounds__(256) void prep_kernel(const float* __restrict__ x,
                                                   const float* __restrict__ gamma,
                                                   const float* __restrict__ beta,
                                                   unsigned short* __restrict__ xn,
                                                   const float* __restrict__ w_qkv,
                                                   unsigned short* __restrict__ wqkvT,
                                                   const float* __restrict__ w_proj,
                                                   unsigned short* __restrict__ wprojT) {
    __shared__ float tile[32][33];
    int blk = blockIdx.x;
    int tid = threadIdx.x;

    if (blk < 4096) {
        const float* xr = x + (size_t)blk * Dd;
        float4 v = ((const float4*)xr)[tid];
        float s = v.x + v.y + v.z + v.w;
        float ss = v.x * v.x + v.y * v.y + v.z * v.z + v.w * v.w;
        for (int o = 32; o > 0; o >>= 1) {
            s += __shfl_down(s, o);
            ss += __shfl_down(ss, o);
        }
        float* red = &tile[0][0];
        int wid = tid >> 6;
        if ((tid & 63) == 0) { red[wid * 2] = s; red[wid * 2 + 1] = ss; }
        __syncthreads();
        float tot = red[0] + red[2] + red[4] + red[6];
        float tot2 = red[1] + red[3] + red[5] + red[7];
        float mu = tot * (1.0f / Dd);
        float var = tot2 * (1.0f / Dd) - mu * mu;
        float inv = rsqrtf(var + LN_EPS);
        float4 g = ((const float4*)gamma)[tid];
        float4 b = ((const float4*)beta)[tid];
        ushort4 o4;
        o4.x = f2bf((v.x - mu) * inv * g.x + b.x);
        o4.y = f2bf((v.y - mu) * inv * g.y + b.y);
        o4.z = f2bf((v.z - mu) * inv * g.z + b.z);
        o4.w = f2bf((v.w - mu) * inv * g.w + b.w);
        ((ushort4*)(xn + (size_t)blk * Dd))[tid] = o4;
    } else {
        const float* in;
        unsigned short* out;
        int cols, c0, r0;
        if (blk < 7168) {
            int idx = blk - 4096;
            in = w_qkv; out = wqkvT; cols = 3072;
            c0 = (idx % 96) * 32; r0 = (idx / 96) * 32;
        } else {
            int idx = blk - 7168;
            in = w_proj; out = wprojT; cols = 1024;
            c0 = (idx % 32) * 32; r0 = (idx / 32) * 32;
        }
        int tx = tid & 31, ty = tid >> 5;
        #pragma unroll
        for (int i = 0; i < 32; i += 8)
            tile[ty + i][tx] = in[(size_t)(r0 + ty + i) * cols + c0 + tx];
        __syncthreads();
        #pragma unroll
        for (int i = 0; i < 32; i += 8)
            out[(size_t)(c0 + ty + i) * 1024 + r0 + tx] = f2bf(tile[tx][ty + i]);
    }
}

// ========== GEMM body: 128x128 tile, BK=64 (32 MFMA / barrier pair) ========
// -------- QKV GEMM: xn[4096][1024] @ wqkvT[3072][1024] -> q/k/vt scatter ----
__global__ __launch_bounds__(256) void gemm_qkv(const unsigned short* __restrict__ A,
                                                const unsigned short* __restrict__ Bt,
                                                unsigned short* __restrict__ qb,
                                                unsigned short* __restrict__ kb,
                                                unsigned short* __restrict__ vtb) {
    __shared__ unsigned short sA[8192], sB[8192];
    int tid = threadIdx.x;
    int w = tid >> 6, lane = tid & 63, lrow = lane & 15, quad = lane >> 4;
    int wm = w >> 1, wn = w & 1;
    int rowbase = blockIdx.y * 128;
    int colbase = blockIdx.x * 128;

    int srow = tid >> 3;
    int gch = ((tid & 7) - (srow >> 1)) & 7;
    const unsigned short* gA = A + (size_t)(rowbase + srow) * 1024 + gch * 8;
    const unsigned short* gB = Bt + (size_t)(colbase + srow) * 1024 + gch * 8;
    unsigned short* lA = sA + w * 512;
    unsigned short* lB = sB + w * 512;

    int bs0 = ((quad + (lrow >> 1)) & 7) * 8;
    int bs1 = ((4 + quad + (lrow >> 1)) & 7) * 8;
    const unsigned short* fa = sA + (wm * 64 + lrow) * 64;
    const unsigned short* fb = sB + (wn * 64 + lrow) * 64;

    f32x4 acc[4][4];
    #pragma unroll
    for (int i = 0; i < 4; i++)
        #pragma unroll
        for (int j = 0; j < 4; j++)
            acc[i][j] = (f32x4){0.f, 0.f, 0.f, 0.f};

    for (int k0 = 0; k0 < 1024; k0 += 64) {
        __syncthreads();
        #pragma unroll
        for (int c = 0; c < 4; c++) {
            glds16(gA + (size_t)c * 32768 + k0, lA + c * 2048);
            glds16(gB + (size_t)c * 32768 + k0, lB + c * 2048);
        }
        __syncthreads();
        #pragma unroll
        for (int s = 0; s < 2; s++) {
            int bo = s ? bs1 : bs0;
            bf16x8 a[4], b[4];
            #pragma unroll
            for (int i = 0; i < 4; i++) a[i] = *(const bf16x8*)(fa + i * 1024 + bo);
            #pragma unroll
            for (int j = 0; j < 4; j++) b[j] = *(const bf16x8*)(fb + j * 1024 + bo);
            #pragma unroll
            for (int i = 0; i < 4; i++)
                #pragma unroll
                for (int j = 0; j < 4; j++)
                    acc[i][j] = __builtin_amdgcn_mfma_f32_16x16x32_bf16(a[i], b[j], acc[i][j], 0, 0, 0);
        }
    }

    #pragma unroll
    for (int j = 0; j < 4; j++) {
        int colg = colbase + wn * 64 + j * 16;
        int s = colg >> 10, rem = colg & 1023;
        int h = rem >> 6;
        int e = (rem & 63) + lrow;
        if (s < 2) {
            unsigned short* dst = (s == 0) ? qb : kb;
            #pragma unroll
            for (int i = 0; i < 4; i++) {
                #pragma unroll
                for (int r = 0; r < 4; r++) {
                    int R = rowbase + wm * 64 + i * 16 + quad * 4 + r;
                    int bb = R >> 10, n = R & 1023;
                    dst[(((size_t)(bb * Hh + h)) * Nn + n) * HD + e] = f2bf(acc[i][j][r]);
                }
            }
        } else {
            // v: lane's r=0..3 are consecutive tokens n -> packed 8B store
            #pragma unroll
            for (int i = 0; i < 4; i++) {
                int R0 = rowbase + wm * 64 + i * 16 + quad * 4;
                int bb = R0 >> 10, n0v = R0 & 1023;
                uint2 pk;
                pk.x = pack2bf(acc[i][j][0], acc[i][j][1]);
                pk.y = pack2bf(acc[i][j][2], acc[i][j][3]);
                *(uint2*)(vtb + ((size_t)((bb * Hh + h) * HD) + e) * Nn + n0v) = pk;
            }
        }
    }
}

// ---- proj GEMM: aout[4096][1024] @ wprojT[1024][1024] + bias + x -> out ----
__global__ __launch_bounds__(256) void gemm_proj(const unsigned short* __restrict__ A,
                                                 const unsigned short* __restrict__ Bt,
                                                 const float* __restrict__ bias,
                                                 const float* __restrict__ x,
                                                 float* __restrict__ out) {
    __shared__ unsigned short sA[8192], sB[8192];
    int tid = threadIdx.x;
    int w = tid >> 6, lane = tid & 63, lrow = lane & 15, quad = lane >> 4;
    int wm = w >> 1, wn = w & 1;
    int rowbase = blockIdx.y * 128;
    int colbase = blockIdx.x * 128;

    int srow = tid >> 3;
    int gch = ((tid & 7) - (srow >> 1)) & 7;
    const unsigned short* gA = A + (size_t)(rowbase + srow) * 1024 + gch * 8;
    const unsigned short* gB = Bt + (size_t)(colbase + srow) * 1024 + gch * 8;
    unsigned short* lA = sA + w * 512;
    unsigned short* lB = sB + w * 512;

    int bs0 = ((quad + (lrow >> 1)) & 7) * 8;
    int bs1 = ((4 + quad + (lrow >> 1)) & 7) * 8;
    const unsigned short* fa = sA + (wm * 64 + lrow) * 64;
    const unsigned short* fb = sB + (wn * 64 + lrow) * 64;

    f32x4 acc[4][4];
    #pragma unroll
    for (int i = 0; i < 4; i++)
        #pragma unroll
        for (int j = 0; j < 4; j++)
            acc[i][j] = (f32x4){0.f, 0.f, 0.f, 0.f};

    for (int k0 = 0; k0 < 1024; k0 += 64) {
        __syncthreads();
        #pragma unroll
        for (int c = 0; c < 4; c++) {
            glds16(gA + (size_t)c * 32768 + k0, lA + c * 2048);
            glds16(gB + (size_t)c * 32768 + k0, lB + c * 2048);
        }
        __syncthreads();
        #pragma unroll
        for (int s = 0; s < 2; s++) {
            int bo = s ? bs1 : bs0;
            bf16x8 a[4], b[4];
            #pragma unroll
            for (int i = 0; i < 4; i++) a[i] = *(const bf16x8*)(fa + i * 1024 + bo);
            #pragma unroll
            for (int j = 0; j < 4; j++) b[j] = *(const bf16x8*)(fb + j * 1024 + bo);
            #pragma unroll
            for (int i = 0; i < 4; i++)
                #pragma unroll
                for (int j = 0; j < 4; j++)
                    acc[i][j] = __builtin_amdgcn_mfma_f32_16x16x32_bf16(a[i], b[j], acc[i][j], 0, 0, 0);
        }
    }

    #pragma unroll
    for (int j = 0; j < 4; j++) {
        int col = colbase + wn * 64 + j * 16 + lrow;
        float bc = bias[col];
        #pragma unroll
        for (int i = 0; i < 4; i++) {
            #pragma unroll
            for (int r = 0; r < 4; r++) {
                int R = rowbase + wm * 64 + i * 16 + quad * 4 + r;
                out[(size_t)R * 1024 + col] = acc[i][j][r] + bc + x[(size_t)R * 1024 + col];
            }
        }
    }
}

// ============ fused attention v4.1: block = (b, h, 128 q-rows) =============
// Swapped QK (S = K·Q^T); wave owns 32 q-rows; m-tile = 64 keys; no max pass.
// exp2f with folded log2e; v_cvt_pk_bf16_f32 packing; sim read as fp32.
#define PSTR 72   // sP row stride in shorts (144 B)
__global__ __launch_bounds__(256) void attn_kernel(const unsigned short* __restrict__ qb,
                                                   const unsigned short* __restrict__ kb,
                                                   const unsigned short* __restrict__ vtb,
                                                   const float* __restrict__ sim,
                                                   const float* __restrict__ swl,
                                                   unsigned short* __restrict__ aout) {
    int h = blockIdx.y, bb = blockIdx.z;
    int n0 = blockIdx.x * 128;
    int tid = threadIdx.x;
    int w = tid >> 6, lane = tid & 63;
    int lrow = lane & 15, quad = lane >> 4;
    const unsigned short* q = qb + ((size_t)(bb * Hh + h)) * Nn * HD;
    const unsigned short* k = kb + ((size_t)(bb * Hh + h)) * Nn * HD;
    const unsigned short* vt = vtb + ((size_t)(bb * Hh + h)) * HD * Nn;
    float alpha = 1.f / (1.f + __expf(-swl[0]));
    const float L2E = 1.44269504f;
    float c1 = (1.f - alpha) * SCALE * L2E;
    float aL = alpha * L2E;

    __shared__ unsigned short sK[4096];        // [64 keys][64 d], chunk-swizzled
    __shared__ unsigned short sV[4096];        // [64 e][64 keys], chunk-swizzled
    __shared__ unsigned short sP[128 * PSTR];  // [128 qrows][64 keys + pad]

    int qr0 = n0 + w * 32;
    bf16x8 qf[2][2];
    #pragma unroll
    for (int g = 0; g < 2; g++) {
        qf[g][0] = ldfrag(q + (size_t)(qr0 + g * 16 + lrow) * HD + quad * 8);
        qf[g][1] = ldfrag(q + (size_t)(qr0 + g * 16 + lrow) * HD + 32 + quad * 8);
    }

    f32x4 o[2][4];
    #pragma unroll
    for (int g = 0; g < 2; g++)
        #pragma unroll
        for (int et = 0; et < 4; et++) o[g][et] = (f32x4){0.f, 0.f, 0.f, 0.f};
    float rsum[2] = {0.f, 0.f};

    int bs0 = (quad + (lrow >> 1)) & 7;
    int bs1 = (4 + quad + (lrow >> 1)) & 7;
    unsigned short* sPw = sP + (w * 32) * PSTR;

    for (int m0 = 0; m0 < 1024; m0 += 64) {
        __syncthreads();
        #pragma unroll
        for (int i = 0; i < 2; i++) {
            int slot = i * 256 + tid;
            int row = slot >> 3;
            int cg = ((slot & 7) - (row >> 1)) & 7;
            glds16(k + (size_t)(m0 + row) * HD + cg * 8, sK + i * 2048 + w * 512);
        }
        #pragma unroll
        for (int i = 0; i < 2; i++) {
            int slot = i * 256 + tid;
            int row = slot >> 3;
            int cg = ((slot & 7) - (row >> 1)) & 7;
            glds16(vt + (size_t)row * Nn + m0 + cg * 8, sV + i * 2048 + w * 512);
        }
        float4 sm[4][2];
        #pragma unroll
        for (int ks = 0; ks < 4; ks++)
            #pragma unroll
            for (int g = 0; g < 2; g++)
                sm[ks][g] = *(const float4*)(sim + (size_t)(qr0 + g * 16 + lrow) * Nn
                                             + m0 + ks * 16 + quad * 4);
        __syncthreads();

        #pragma unroll
        for (int ks = 0; ks < 4; ks++) {
            const unsigned short* kr = sK + (ks * 16 + lrow) * 64;
            bf16x8 ak0 = *(const bf16x8*)(kr + bs0 * 8);
            bf16x8 ak1 = *(const bf16x8*)(kr + bs1 * 8);
            #pragma unroll
            for (int g = 0; g < 2; g++) {
                f32x4 c = (f32x4){0.f, 0.f, 0.f, 0.f};
                c = __builtin_amdgcn_mfma_f32_16x16x32_bf16(ak0, qf[g][0], c, 0, 0, 0);
                c = __builtin_amdgcn_mfma_f32_16x16x32_bf16(ak1, qf[g][1], c, 0, 0, 0);
                float e0 = exp2f(c1 * c[0] + aL * sm[ks][g].x);
                float e1 = exp2f(c1 * c[1] + aL * sm[ks][g].y);
                float e2 = exp2f(c1 * c[2] + aL * sm[ks][g].z);
                float e3 = exp2f(c1 * c[3] + aL * sm[ks][g].w);
                rsum[g] += (e0 + e1) + (e2 + e3);
                uint2 pk;
                pk.x = pack2bf(e0, e1);
                pk.y = pack2bf(e2, e3);
                *(uint2*)(sPw + (g * 16 + lrow) * PSTR + ks * 16 + quad * 4) = pk;
            }
        }

        #pragma unroll
        for (int ms = 0; ms < 2; ms++) {
            bf16x8 pa[2];
            #pragma unroll
            for (int g = 0; g < 2; g++)
                pa[g] = *(const bf16x8*)(sPw + (g * 16 + lrow) * PSTR + ms * 32 + quad * 8);
            #pragma unroll
            for (int et = 0; et < 4; et++) {
                int e = et * 16 + lrow;
                int slot = (ms * 4 + quad + (e >> 1)) & 7;
                bf16x8 vb = *(const bf16x8*)(sV + e * 64 + slot * 8);
                #pragma unroll
                for (int g = 0; g < 2; g++)
                    o[g][et] = __builtin_amdgcn_mfma_f32_16x16x32_bf16(pa[g], vb, o[g][et], 0, 0, 0);
            }
        }
    }

    #pragma unroll
    for (int g = 0; g < 2; g++) {
        rsum[g] += __shfl_xor(rsum[g], 16);
        rsum[g] += __shfl_xor(rsum[g], 32);
    }

    #pragma unroll
    for (int g = 0; g < 2; g++)
        #pragma unroll
        for (int r = 0; r < 4; r++) {
            float inv = 1.f / __shfl(rsum[g], quad * 4 + r);
            int qn = qr0 + g * 16 + quad * 4 + r;
            #pragma unroll
            for (int et = 0; et < 4; et++)
                aout[((size_t)bb * Nn + qn) * Dd + h * HD + et * 16 + lrow]
                    = f2bf(o[g][et][r] * inv);
        }
}

extern "C" void kernel_launch(void* const* d_in, const int* in_sizes, int n_in,
                              void* d_out, int out_size, void* d_ws, size_t ws_size,
                              hipStream_t stream) {
    const float* x      = (const float*)d_in[0];
    const float* gamma  = (const float*)d_in[1];
    const float* beta   = (const float*)d_in[2];
    const float* w_qkv  = (const float*)d_in[3];
    const float* w_proj = (const float*)d_in[4];
    const float* b_proj = (const float*)d_in[5];
    const float* swl    = (const float*)d_in[6];
    const float* sim    = (const float*)d_in[7];
    float* out = (float*)d_out;

    unsigned short* ws = (unsigned short*)d_ws;
    unsigned short* xn     = ws;                  // 4096*1024
    unsigned short* wqkvT  = xn + 4194304;        // 3072*1024
    unsigned short* wprojT = wqkvT + 3145728;     // 1024*1024
    unsigned short* qb     = wprojT + 1048576;    // 4*16*1024*64
    unsigned short* kb     = qb + 4194304;
    unsigned short* vtb    = kb + 4194304;
    unsigned short* aout   = vtb + 4194304;       // 4096*1024

    prep_kernel<<<8192, 256, 0, stream>>>(x, gamma, beta, xn, w_qkv, wqkvT, w_proj, wprojT);
    gemm_qkv<<<dim3(24, 32), 256, 0, stream>>>(xn, wqkvT, qb, kb, vtb);
    attn_kernel<<<dim3(8, 16, 4), 256, 0, stream>>>(qb, kb, vtb, sim, swl, aout);
    gemm_proj<<<dim3(8, 32), 256, 0, stream>>>(aout, wprojT, b_proj, x, out);
}

// Round 12
// 201.330 us; speedup vs baseline: 1.9677x; 1.0209x over previous
//
#include <hip/hip_runtime.h>

#define Bz 4
#define Nn 1024
#define Dd 1024
#define Hh 16
#define HD 64
#define SCALE 0.125f
#define LN_EPS 1e-5f

typedef __attribute__((ext_vector_type(8))) __bf16 bf16x8;
typedef __attribute__((ext_vector_type(4))) float f32x4;

static __device__ inline unsigned short f2bf(float f) {
    unsigned int u = __float_as_uint(f);
    u += 0x7fffu + ((u >> 16) & 1u);   // round-to-nearest-even
    return (unsigned short)(u >> 16);
}

static __device__ inline bf16x8 ldfrag(const unsigned short* p) {
    return *(const bf16x8*)p;
}

static __device__ __forceinline__ void glds16(const unsigned short* g, unsigned short* l) {
    __builtin_amdgcn_global_load_lds((const __attribute__((address_space(1))) void*)g,
                                     (__attribute__((address_space(3))) void*)l, 16, 0, 0);
}

// ===== prep: LN (blocks 0..4095) + transpose w_qkv (4096..7167) +
//             transpose w_proj (7168..8191), all 256-thread blocks ==========
__global__ __launch_bounds__(256) void prep_kernel(const float* __restrict__ x,
                                                   const float* __restrict__ gamma,
                                                   const float* __restrict__ beta,
                                                   unsigned short* __restrict__ xn,
                                                   const float* __restrict__ w_qkv,
                                                   unsigned short* __restrict__ wqkvT,
                                                   const float* __restrict__ w_proj,
                                                   unsigned short* __restrict__ wprojT) {
    __shared__ float tile[32][33];
    int blk = blockIdx.x;
    int tid = threadIdx.x;

    if (blk < 4096) {
        const float* xr = x + (size_t)blk * Dd;
        float4 v = ((const float4*)xr)[tid];
        float s = v.x + v.y + v.z + v.w;
        float ss = v.x * v.x + v.y * v.y + v.z * v.z + v.w * v.w;
        for (int o = 32; o > 0; o >>= 1) {
            s += __shfl_down(s, o);
            ss += __shfl_down(ss, o);
        }
        float* red = &tile[0][0];
        int wid = tid >> 6;
        if ((tid & 63) == 0) { red[wid * 2] = s; red[wid * 2 + 1] = ss; }
        __syncthreads();
        float tot = red[0] + red[2] + red[4] + red[6];
        float tot2 = red[1] + red[3] + red[5] + red[7];
        float mu = tot * (1.0f / Dd);
        float var = tot2 * (1.0f / Dd) - mu * mu;
        float inv = rsqrtf(var + LN_EPS);
        float4 g = ((const float4*)gamma)[tid];
        float4 b = ((const float4*)beta)[tid];
        ushort4 o4;
        o4.x = f2bf((v.x - mu) * inv * g.x + b.x);
        o4.y = f2bf((v.y - mu) * inv * g.y + b.y);
        o4.z = f2bf((v.z - mu) * inv * g.z + b.z);
        o4.w = f2bf((v.w - mu) * inv * g.w + b.w);
        ((ushort4*)(xn + (size_t)blk * Dd))[tid] = o4;
    } else {
        const float* in;
        unsigned short* out;
        int cols, c0, r0;
        if (blk < 7168) {
            int idx = blk - 4096;
            in = w_qkv; out = wqkvT; cols = 3072;
            c0 = (idx % 96) * 32; r0 = (idx / 96) * 32;
        } else {
            int idx = blk - 7168;
            in = w_proj; out = wprojT; cols = 1024;
            c0 = (idx % 32) * 32; r0 = (idx / 32) * 32;
        }
        int tx = tid & 31, ty = tid >> 5;
        #pragma unroll
        for (int i = 0; i < 32; i += 8)
            tile[ty + i][tx] = in[(size_t)(r0 + ty + i) * cols + c0 + tx];
        __syncthreads();
        #pragma unroll
        for (int i = 0; i < 32; i += 8)
            out[(size_t)(c0 + ty + i) * 1024 + r0 + tx] = f2bf(tile[tx][ty + i]);
    }
}

// ========== GEMM body: 128x128 tile, BK=64 (32 MFMA / barrier pair) ========
// -------- QKV GEMM: xn[4096][1024] @ wqkvT[3072][1024] -> q/k/vt scatter ----
__global__ __launch_bounds__(256) void gemm_qkv(const unsigned short* __restrict__ A,
                                                const unsigned short* __restrict__ Bt,
                                                unsigned short* __restrict__ qb,
                                                unsigned short* __restrict__ kb,
                                                unsigned short* __restrict__ vtb) {
    __shared__ unsigned short sA[8192], sB[8192];
    int tid = threadIdx.x;
    int w = tid >> 6, lane = tid & 63, lrow = lane & 15, quad = lane >> 4;
    int wm = w >> 1, wn = w & 1;
    int rowbase = blockIdx.y * 128;
    int colbase = blockIdx.x * 128;

    int srow = tid >> 3;
    int gch = ((tid & 7) - (srow >> 1)) & 7;
    const unsigned short* gA = A + (size_t)(rowbase + srow) * 1024 + gch * 8;
    const unsigned short* gB = Bt + (size_t)(colbase + srow) * 1024 + gch * 8;
    unsigned short* lA = sA + w * 512;
    unsigned short* lB = sB + w * 512;

    int bs0 = ((quad + (lrow >> 1)) & 7) * 8;
    int bs1 = ((4 + quad + (lrow >> 1)) & 7) * 8;
    const unsigned short* fa = sA + (wm * 64 + lrow) * 64;
    const unsigned short* fb = sB + (wn * 64 + lrow) * 64;

    f32x4 acc[4][4];
    #pragma unroll
    for (int i = 0; i < 4; i++)
        #pragma unroll
        for (int j = 0; j < 4; j++)
            acc[i][j] = (f32x4){0.f, 0.f, 0.f, 0.f};

    for (int k0 = 0; k0 < 1024; k0 += 64) {
        __syncthreads();
        #pragma unroll
        for (int c = 0; c < 4; c++) {
            glds16(gA + (size_t)c * 32768 + k0, lA + c * 2048);
            glds16(gB + (size_t)c * 32768 + k0, lB + c * 2048);
        }
        __syncthreads();
        #pragma unroll
        for (int s = 0; s < 2; s++) {
            int bo = s ? bs1 : bs0;
            bf16x8 a[4], b[4];
            #pragma unroll
            for (int i = 0; i < 4; i++) a[i] = *(const bf16x8*)(fa + i * 1024 + bo);
            #pragma unroll
            for (int j = 0; j < 4; j++) b[j] = *(const bf16x8*)(fb + j * 1024 + bo);
            #pragma unroll
            for (int i = 0; i < 4; i++)
                #pragma unroll
                for (int j = 0; j < 4; j++)
                    acc[i][j] = __builtin_amdgcn_mfma_f32_16x16x32_bf16(a[i], b[j], acc[i][j], 0, 0, 0);
        }
    }

    #pragma unroll
    for (int j = 0; j < 4; j++) {
        int colg = colbase + wn * 64 + j * 16;
        int s = colg >> 10, rem = colg & 1023;
        int h = rem >> 6;
        int e = (rem & 63) + lrow;
        if (s < 2) {
            unsigned short* dst = (s == 0) ? qb : kb;
            #pragma unroll
            for (int i = 0; i < 4; i++) {
                #pragma unroll
                for (int r = 0; r < 4; r++) {
                    int R = rowbase + wm * 64 + i * 16 + quad * 4 + r;
                    int bb = R >> 10, n = R & 1023;
                    dst[(((size_t)(bb * Hh + h)) * Nn + n) * HD + e] = f2bf(acc[i][j][r]);
                }
            }
        } else {
            // v: lane's r=0..3 are consecutive tokens n -> packed 8B store
            #pragma unroll
            for (int i = 0; i < 4; i++) {
                int R0 = rowbase + wm * 64 + i * 16 + quad * 4;
                int bb = R0 >> 10, n0v = R0 & 1023;
                uint2 pk;
                pk.x = (unsigned)f2bf(acc[i][j][0]) | ((unsigned)f2bf(acc[i][j][1]) << 16);
                pk.y = (unsigned)f2bf(acc[i][j][2]) | ((unsigned)f2bf(acc[i][j][3]) << 16);
                *(uint2*)(vtb + ((size_t)((bb * Hh + h) * HD) + e) * Nn + n0v) = pk;
            }
        }
    }
}

// ---- proj GEMM: aout[4096][1024] @ wprojT[1024][1024] + bias + x -> out ----
__global__ __launch_bounds__(256) void gemm_proj(const unsigned short* __restrict__ A,
                                                 const unsigned short* __restrict__ Bt,
                                                 const float* __restrict__ bias,
                                                 const float* __restrict__ x,
                                                 float* __restrict__ out) {
    __shared__ unsigned short sA[8192], sB[8192];
    int tid = threadIdx.x;
    int w = tid >> 6, lane = tid & 63, lrow = lane & 15, quad = lane >> 4;
    int wm = w >> 1, wn = w & 1;
    int rowbase = blockIdx.y * 128;
    int colbase = blockIdx.x * 128;

    int srow = tid >> 3;
    int gch = ((tid & 7) - (srow >> 1)) & 7;
    const unsigned short* gA = A + (size_t)(rowbase + srow) * 1024 + gch * 8;
    const unsigned short* gB = Bt + (size_t)(colbase + srow) * 1024 + gch * 8;
    unsigned short* lA = sA + w * 512;
    unsigned short* lB = sB + w * 512;

    int bs0 = ((quad + (lrow >> 1)) & 7) * 8;
    int bs1 = ((4 + quad + (lrow >> 1)) & 7) * 8;
    const unsigned short* fa = sA + (wm * 64 + lrow) * 64;
    const unsigned short* fb = sB + (wn * 64 + lrow) * 64;

    f32x4 acc[4][4];
    #pragma unroll
    for (int i = 0; i < 4; i++)
        #pragma unroll
        for (int j = 0; j < 4; j++)
            acc[i][j] = (f32x4){0.f, 0.f, 0.f, 0.f};

    for (int k0 = 0; k0 < 1024; k0 += 64) {
        __syncthreads();
        #pragma unroll
        for (int c = 0; c < 4; c++) {
            glds16(gA + (size_t)c * 32768 + k0, lA + c * 2048);
            glds16(gB + (size_t)c * 32768 + k0, lB + c * 2048);
        }
        __syncthreads();
        #pragma unroll
        for (int s = 0; s < 2; s++) {
            int bo = s ? bs1 : bs0;
            bf16x8 a[4], b[4];
            #pragma unroll
            for (int i = 0; i < 4; i++) a[i] = *(const bf16x8*)(fa + i * 1024 + bo);
            #pragma unroll
            for (int j = 0; j < 4; j++) b[j] = *(const bf16x8*)(fb + j * 1024 + bo);
            #pragma unroll
            for (int i = 0; i < 4; i++)
                #pragma unroll
                for (int j = 0; j < 4; j++)
                    acc[i][j] = __builtin_amdgcn_mfma_f32_16x16x32_bf16(a[i], b[j], acc[i][j], 0, 0, 0);
        }
    }

    #pragma unroll
    for (int j = 0; j < 4; j++) {
        int col = colbase + wn * 64 + j * 16 + lrow;
        float bc = bias[col];
        #pragma unroll
        for (int i = 0; i < 4; i++) {
            #pragma unroll
            for (int r = 0; r < 4; r++) {
                int R = rowbase + wm * 64 + i * 16 + quad * 4 + r;
                out[(size_t)R * 1024 + col] = acc[i][j][r] + bc + x[(size_t)R * 1024 + col];
            }
        }
    }
}

// ============ fused attention v4 (round-8 exact): (b, h, 128 q-rows) =======
// Swapped QK (S = K·Q^T); wave owns 32 q-rows; m-tile = 64 keys; no max pass.
// __expf + truncation packing (pack2bf-RNE regressed: no HW pk-bf16 lowering).
#define PSTR 72   // sP row stride in shorts (144 B)
__global__ __launch_bounds__(256) void attn_kernel(const unsigned short* __restrict__ qb,
                                                   const unsigned short* __restrict__ kb,
                                                   const unsigned short* __restrict__ vtb,
                                                   const float* __restrict__ sim,
                                                   const float* __restrict__ swl,
                                                   unsigned short* __restrict__ aout) {
    int h = blockIdx.y, bb = blockIdx.z;
    int n0 = blockIdx.x * 128;
    int tid = threadIdx.x;
    int w = tid >> 6, lane = tid & 63;
    int lrow = lane & 15, quad = lane >> 4;
    const unsigned short* q = qb + ((size_t)(bb * Hh + h)) * Nn * HD;
    const unsigned short* k = kb + ((size_t)(bb * Hh + h)) * Nn * HD;
    const unsigned short* vt = vtb + ((size_t)(bb * Hh + h)) * HD * Nn;
    float alpha = 1.f / (1.f + __expf(-swl[0]));
    float c1 = (1.f - alpha) * SCALE;

    __shared__ unsigned short sK[4096];        // [64 keys][64 d], chunk-swizzled
    __shared__ unsigned short sV[4096];        // [64 e][64 keys], chunk-swizzled
    __shared__ unsigned short sP[128 * PSTR];  // [128 qrows][64 keys + pad]

    int qr0 = n0 + w * 32;
    bf16x8 qf[2][2];
    #pragma unroll
    for (int g = 0; g < 2; g++) {
        qf[g][0] = ldfrag(q + (size_t)(qr0 + g * 16 + lrow) * HD + quad * 8);
        qf[g][1] = ldfrag(q + (size_t)(qr0 + g * 16 + lrow) * HD + 32 + quad * 8);
    }

    f32x4 o[2][4];
    #pragma unroll
    for (int g = 0; g < 2; g++)
        #pragma unroll
        for (int et = 0; et < 4; et++) o[g][et] = (f32x4){0.f, 0.f, 0.f, 0.f};
    float rsum[2] = {0.f, 0.f};

    int bs0 = (quad + (lrow >> 1)) & 7;
    int bs1 = (4 + quad + (lrow >> 1)) & 7;
    unsigned short* sPw = sP + (w * 32) * PSTR;

    for (int m0 = 0; m0 < 1024; m0 += 64) {
        __syncthreads();
        #pragma unroll
        for (int i = 0; i < 2; i++) {
            int slot = i * 256 + tid;
            int row = slot >> 3;
            int cg = ((slot & 7) - (row >> 1)) & 7;
            glds16(k + (size_t)(m0 + row) * HD + cg * 8, sK + i * 2048 + w * 512);
        }
        #pragma unroll
        for (int i = 0; i < 2; i++) {
            int slot = i * 256 + tid;
            int row = slot >> 3;
            int cg = ((slot & 7) - (row >> 1)) & 7;
            glds16(vt + (size_t)row * Nn + m0 + cg * 8, sV + i * 2048 + w * 512);
        }
        float4 sm[4][2];
        #pragma unroll
        for (int ks = 0; ks < 4; ks++)
            #pragma unroll
            for (int g = 0; g < 2; g++)
                sm[ks][g] = *(const float4*)(sim + (size_t)(qr0 + g * 16 + lrow) * Nn
                                             + m0 + ks * 16 + quad * 4);
        __syncthreads();

        #pragma unroll
        for (int ks = 0; ks < 4; ks++) {
            const unsigned short* kr = sK + (ks * 16 + lrow) * 64;
            bf16x8 ak0 = *(const bf16x8*)(kr + bs0 * 8);
            bf16x8 ak1 = *(const bf16x8*)(kr + bs1 * 8);
            #pragma unroll
            for (int g = 0; g < 2; g++) {
                f32x4 c = (f32x4){0.f, 0.f, 0.f, 0.f};
                c = __builtin_amdgcn_mfma_f32_16x16x32_bf16(ak0, qf[g][0], c, 0, 0, 0);
                c = __builtin_amdgcn_mfma_f32_16x16x32_bf16(ak1, qf[g][1], c, 0, 0, 0);
                float e0 = __expf(c1 * c[0] + alpha * sm[ks][g].x);
                float e1 = __expf(c1 * c[1] + alpha * sm[ks][g].y);
                float e2 = __expf(c1 * c[2] + alpha * sm[ks][g].z);
                float e3 = __expf(c1 * c[3] + alpha * sm[ks][g].w);
                rsum[g] += (e0 + e1) + (e2 + e3);
                uint2 pk;
                pk.x = (__float_as_uint(e0) >> 16) | (__float_as_uint(e1) & 0xffff0000u);
                pk.y = (__float_as_uint(e2) >> 16) | (__float_as_uint(e3) & 0xffff0000u);
                *(uint2*)(sPw + (g * 16 + lrow) * PSTR + ks * 16 + quad * 4) = pk;
            }
        }

        #pragma unroll
        for (int ms = 0; ms < 2; ms++) {
            bf16x8 pa[2];
            #pragma unroll
            for (int g = 0; g < 2; g++)
                pa[g] = *(const bf16x8*)(sPw + (g * 16 + lrow) * PSTR + ms * 32 + quad * 8);
            #pragma unroll
            for (int et = 0; et < 4; et++) {
                int e = et * 16 + lrow;
                int slot = (ms * 4 + quad + (e >> 1)) & 7;
                bf16x8 vb = *(const bf16x8*)(sV + e * 64 + slot * 8);
                #pragma unroll
                for (int g = 0; g < 2; g++)
                    o[g][et] = __builtin_amdgcn_mfma_f32_16x16x32_bf16(pa[g], vb, o[g][et], 0, 0, 0);
            }
        }
    }

    #pragma unroll
    for (int g = 0; g < 2; g++) {
        rsum[g] += __shfl_xor(rsum[g], 16);
        rsum[g] += __shfl_xor(rsum[g], 32);
    }

    #pragma unroll
    for (int g = 0; g < 2; g++)
        #pragma unroll
        for (int r = 0; r < 4; r++) {
            float inv = 1.f / __shfl(rsum[g], quad * 4 + r);
            int qn = qr0 + g * 16 + quad * 4 + r;
            #pragma unroll
            for (int et = 0; et < 4; et++)
                aout[((size_t)bb * Nn + qn) * Dd + h * HD + et * 16 + lrow]
                    = f2bf(o[g][et][r] * inv);
        }
}

extern "C" void kernel_launch(void* const* d_in, const int* in_sizes, int n_in,
                              void* d_out, int out_size, void* d_ws, size_t ws_size,
                              hipStream_t stream) {
    const float* x      = (const float*)d_in[0];
    const float* gamma  = (const float*)d_in[1];
    const float* beta   = (const float*)d_in[2];
    const float* w_qkv  = (const float*)d_in[3];
    const float* w_proj = (const float*)d_in[4];
    const float* b_proj = (const float*)d_in[5];
    const float* swl    = (const float*)d_in[6];
    const float* sim    = (const float*)d_in[7];
    float* out = (float*)d_out;

    unsigned short* ws = (unsigned short*)d_ws;
    unsigned short* xn     = ws;                  // 4096*1024
    unsigned short* wqkvT  = xn + 4194304;        // 3072*1024
    unsigned short* wprojT = wqkvT + 3145728;     // 1024*1024
    unsigned short* qb     = wprojT + 1048576;    // 4*16*1024*64
    unsigned short* kb     = qb + 4194304;
    unsigned short* vtb    = kb + 4194304;
    unsigned short* aout   = vtb + 4194304;       // 4096*1024

    prep_kernel<<<8192, 256, 0, stream>>>(x, gamma, beta, xn, w_qkv, wqkvT, w_proj, wprojT);
    gemm_qkv<<<dim3(24, 32), 256, 0, stream>>>(xn, wqkvT, qb, kb, vtb);
    attn_kernel<<<dim3(8, 16, 4), 256, 0, stream>>>(qb, kb, vtb, sim, swl, aout);
    gemm_proj<<<dim3(8, 32), 256, 0, stream>>>(aout, wprojT, b_proj, x, out);
}